// Round 3
// baseline (205.929 us; speedup 1.0000x reference)
//
#include <hip/hip_runtime.h>

// ZGate, D=4, S=1, INDEX=(0,2,5,8), L=10, N=4^10=1048576, B=16.
// phase(n) = i^t, t = ((n>>18)+(n>>14)+(n>>8)+(n>>2)) & 3   (bit-pair digits of n)
// Input x: [2, N, B] float32 planar (re plane then im plane).
// Output (complex case): interleaved (re,im) float pairs, out_size = 2*N*B.
// Fallback (real case): out_size = N*B floats, real part only.

#define NSTATES (1u << 20)   // 4^10
#define BATCH   16u

__device__ __forceinline__ void phase_for(unsigned n, float& c, float& s) {
    unsigned t = ((n >> 18) + (n >> 14) + (n >> 8) + (n >> 2)) & 3u;
    // i^t: (c, s) = (Re, Im)
    c = (t & 1u) ? 0.0f : ((t & 2u) ? -1.0f : 1.0f);
    s = (t & 1u) ? ((t & 2u) ? -1.0f : 1.0f) : 0.0f;
}

// Interleaved complex output, fully lane-contiguous stores:
// thread j owns output float4 j = complex elements (2j, 2j+1).
// Both share the same n (2j even, 2j+1 odd, B=16): n = j >> 3.
__global__ __launch_bounds__(256) void zgate_cplx_v2(const float* __restrict__ x,
                                                     float* __restrict__ out) {
    unsigned j = blockIdx.x * blockDim.x + threadIdx.x;     // [0, N*B/2)
    unsigned n = j >> 3;

    const float2 re = reinterpret_cast<const float2*>(x)[j];
    const float2 im = reinterpret_cast<const float2*>(x + (size_t)NSTATES * BATCH)[j];

    float c, s;
    phase_for(n, c, s);

    float4 o;
    o.x = c * re.x - s * im.x;
    o.y = s * re.x + c * im.x;
    o.z = c * re.y - s * im.y;
    o.w = s * re.y + c * im.y;
    reinterpret_cast<float4*>(out)[j] = o;
}

// Real-part-only output: out[n,b] = c*re - s*im, N*B floats. Already ideal.
__global__ __launch_bounds__(256) void zgate_real(const float* __restrict__ x,
                                                  float* __restrict__ out) {
    unsigned tid = blockIdx.x * blockDim.x + threadIdx.x;   // [0, N*B/4)
    unsigned n = tid >> 2;

    float4 re = reinterpret_cast<const float4*>(x)[tid];
    float4 im = reinterpret_cast<const float4*>(x + (size_t)NSTATES * BATCH)[tid];

    float c, s;
    phase_for(n, c, s);

    float4 o;
    o.x = c * re.x - s * im.x;
    o.y = c * re.y - s * im.y;
    o.z = c * re.z - s * im.z;
    o.w = c * re.w - s * im.w;
    reinterpret_cast<float4*>(out)[tid] = o;
}

extern "C" void kernel_launch(void* const* d_in, const int* in_sizes, int n_in,
                              void* d_out, int out_size, void* d_ws, size_t ws_size,
                              hipStream_t stream) {
    const float* x = (const float*)d_in[0];
    float* out = (float*)d_out;

    const unsigned NB = NSTATES * BATCH;          // 16,777,216
    dim3 block(256);

    if ((unsigned)out_size >= 2u * NB) {
        unsigned threads = NB / 2;                // 8,388,608 (one float4 out each)
        zgate_cplx_v2<<<dim3(threads / 256), block, 0, stream>>>(x, out);
    } else {
        unsigned threads = NB / 4;                // 4,194,304
        zgate_real<<<dim3(threads / 256), block, 0, stream>>>(x, out);
    }
}